// Round 1
// baseline (1118.683 us; speedup 1.0000x reference)
//
#include <hip/hip_runtime.h>
#include <hip/hip_bf16.h>

#define N_NODES 50000
#define N_EDGES 800000
#define D 128
#define NEG_SLOPE 0.2f

// Kernel 1: fused dense transform. comb = X@W, h_r = X@W_r, h_l = X@W_l.
// blockDim = (128, 2): x = output column, y = node within block.
__global__ __launch_bounds__(256) void gemm3_kernel(
    const float* __restrict__ X,
    const float* __restrict__ W,
    const float* __restrict__ W_r,
    const float* __restrict__ W_l,
    float* __restrict__ comb,
    float* __restrict__ h_r,
    float* __restrict__ h_l)
{
    const int c = threadIdx.x;                      // 0..127
    const int node = blockIdx.x * 2 + threadIdx.y;  // 2 nodes per block
    if (node >= N_NODES) return;

    const float* __restrict__ xrow = X + (size_t)node * D;
    float a0 = 0.f, a1 = 0.f, a2 = 0.f;
#pragma unroll 8
    for (int k = 0; k < D; ++k) {
        const float xv = xrow[k];          // wave-uniform -> broadcast
        a0 += xv * W  [k * D + c];         // coalesced across lanes
        a1 += xv * W_r[k * D + c];
        a2 += xv * W_l[k * D + c];
    }
    const size_t o = (size_t)node * D + c;
    comb[o] = a0;
    h_r[o]  = a1;
    h_l[o]  = a2;
}

// Kernel 2: one wave (64 lanes) per edge.
// e = leaky_relu(dot(h_l[src], h_r[dst])); agg[src] += e * comb[dst]
__global__ __launch_bounds__(256) void edge_kernel(
    const float* __restrict__ h_l,
    const float* __restrict__ h_r,
    const float* __restrict__ comb,
    const int* __restrict__ src,
    const int* __restrict__ dst,
    float* __restrict__ agg)
{
    const int wave_in_block = threadIdx.x >> 6;
    const int lane = threadIdx.x & 63;
    const int e_idx = blockIdx.x * 4 + wave_in_block;
    if (e_idx >= N_EDGES) return;

    const int s = src[e_idx];
    const int d = dst[e_idx];

    const float2 al = *(const float2*)(h_l + (size_t)s * D + 2 * lane);
    const float2 ar = *(const float2*)(h_r + (size_t)d * D + 2 * lane);
    float part = al.x * ar.x + al.y * ar.y;

    // wave-wide sum (64 lanes)
#pragma unroll
    for (int m = 32; m > 0; m >>= 1)
        part += __shfl_xor(part, m);

    const float ev = part > 0.f ? part : NEG_SLOPE * part;

    const float2 cb = *(const float2*)(comb + (size_t)d * D + 2 * lane);
    float* outp = agg + (size_t)s * D + 2 * lane;
    atomicAdd(outp,     ev * cb.x);
    atomicAdd(outp + 1, ev * cb.y);
}

extern "C" void kernel_launch(void* const* d_in, const int* in_sizes, int n_in,
                              void* d_out, int out_size, void* d_ws, size_t ws_size,
                              hipStream_t stream) {
    const float* X   = (const float*)d_in[0];
    const float* W   = (const float*)d_in[1];
    const float* W_r = (const float*)d_in[2];
    const float* W_l = (const float*)d_in[3];
    const int* src   = (const int*)d_in[4];
    const int* dst   = (const int*)d_in[5];
    float* agg = (float*)d_out;

    float* comb = (float*)d_ws;                       // 50000*128 floats
    float* h_r  = comb + (size_t)N_NODES * D;
    float* h_l  = h_r  + (size_t)N_NODES * D;

    // zero output (harness poisons it with 0xAA)
    hipMemsetAsync(d_out, 0, (size_t)out_size * sizeof(float), stream);

    dim3 gblock(128, 2, 1);
    gemm3_kernel<<<(N_NODES + 1) / 2, gblock, 0, stream>>>(
        X, W, W_r, W_l, comb, h_r, h_l);

    edge_kernel<<<(N_EDGES + 3) / 4, 256, 0, stream>>>(
        h_l, h_r, comb, src, dst, agg);
}

// Round 2
// 391.813 us; speedup vs baseline: 2.8551x; 2.8551x over previous
//
#include <hip/hip_runtime.h>
#include <hip/hip_bf16.h>

#define N_NODES 50000
#define N_EDGES 800000
#define D 128
#define NEG_SLOPE 0.2f

// ---------------- M = W_l @ W_r^T (128x128, tiny) ----------------
__global__ __launch_bounds__(128) void wlwrt_kernel(const float* __restrict__ W_l,
                                                    const float* __restrict__ W_r,
                                                    float* __restrict__ M) {
    const int a = blockIdx.x;      // row of M
    const int b = threadIdx.x;     // col of M
    float acc = 0.f;
#pragma unroll
    for (int c = 0; c < D; c += 4) {
        const float4 wl = *(const float4*)(W_l + a * D + c);   // wave-uniform
        const float4 wr = *(const float4*)(W_r + b * D + c);   // 64KB table, L1/L2-hot
        acc += wl.x * wr.x + wl.y * wr.y + wl.z * wr.z + wl.w * wr.w;
    }
    M[a * D + b] = acc;
}

// ---------------- C = A @ B   (A [nrows x 128] row-major, B [128 x 128]) ----
// 16 rows per block staged in LDS; 8 rows per thread register-blocked;
// B columns streamed coalesced (256B/wave) through L1.
__global__ __launch_bounds__(256) void dense_nn_kernel(const float* __restrict__ A,
                                                       const float* __restrict__ B,
                                                       float* __restrict__ C,
                                                       int nrows) {
    __shared__ float As[16 * D];
    const int tid = threadIdx.x;
    const int c = tid & 127;
    const int half = tid >> 7;
    const int nb = blockIdx.x * 16;

    // stage 16 contiguous rows = 8KB, fully coalesced float4 copy
    const float4* srcv = (const float4*)(A + (size_t)nb * D);
    float4* dstv = (float4*)As;
    dstv[tid] = srcv[tid];
    dstv[tid + 256] = srcv[tid + 256];
    __syncthreads();

    float acc[8] = {0, 0, 0, 0, 0, 0, 0, 0};
    for (int k = 0; k < D; k += 4) {
        const float m0 = B[(k + 0) * D + c];
        const float m1 = B[(k + 1) * D + c];
        const float m2 = B[(k + 2) * D + c];
        const float m3 = B[(k + 3) * D + c];
#pragma unroll
        for (int n = 0; n < 8; ++n) {
            const float4 xv = *(const float4*)&As[(half * 8 + n) * D + k]; // LDS broadcast
            acc[n] = fmaf(xv.x, m0, fmaf(xv.y, m1, fmaf(xv.z, m2, fmaf(xv.w, m3, acc[n]))));
        }
    }
#pragma unroll
    for (int n = 0; n < 8; ++n)
        C[(size_t)(nb + half * 8 + n) * D + c] = acc[n];
}

// ---------------- CSR build ----------------
__global__ __launch_bounds__(256) void hist_kernel(const int* __restrict__ src,
                                                   int* __restrict__ counts) {
    const int e = blockIdx.x * 256 + threadIdx.x;
    if (e < N_EDGES) atomicAdd(&counts[src[e]], 1);
}

// single-block exclusive scan of 50000 counts -> offsets
__global__ __launch_bounds__(1024) void scan_kernel(const int* __restrict__ counts,
                                                    int* __restrict__ offsets) {
    __shared__ int sums[1024];
    const int t = threadIdx.x;
    const int base = t * 49;                 // 1024*49 = 50176 >= 50000
    int s = 0;
    for (int i = 0; i < 49; ++i) {
        const int idx = base + i;
        if (idx < N_NODES) s += counts[idx];
    }
    sums[t] = s;
    __syncthreads();
    for (int off = 1; off < 1024; off <<= 1) {   // Hillis-Steele inclusive
        const int v = (t >= off) ? sums[t - off] : 0;
        __syncthreads();
        sums[t] += v;
        __syncthreads();
    }
    int run = (t == 0) ? 0 : sums[t - 1];        // exclusive base
    for (int i = 0; i < 49; ++i) {
        const int idx = base + i;
        if (idx < N_NODES) {
            offsets[idx] = run;
            run += counts[idx];
        }
    }
}

// scatter dst grouped by src; consumes offsets (post: offsets[i] = end of row i)
__global__ __launch_bounds__(256) void scatter_kernel(const int* __restrict__ src,
                                                      const int* __restrict__ dst,
                                                      int* __restrict__ offsets,
                                                      int* __restrict__ sorted_dst) {
    const int e = blockIdx.x * 256 + threadIdx.x;
    if (e < N_EDGES) {
        const int pos = atomicAdd(&offsets[src[e]], 1);
        sorted_dst[pos] = dst[e];
    }
}

// ---------------- fused SDDMM + SpMM, no atomics ----------------
// one wave per src node; half-wave (32 lanes x float4 = 512B) per edge;
// X[d] row loaded ONCE, used for both the dot and the accumulation.
__global__ __launch_bounds__(256) void spmm_kernel(const float* __restrict__ hM,
                                                   const float* __restrict__ X,
                                                   const int* __restrict__ offsets,
                                                   const int* __restrict__ sorted_dst,
                                                   float* __restrict__ aggX) {
    const int wave = threadIdx.x >> 6;
    const int lane = threadIdx.x & 63;
    const int node = blockIdx.x * 4 + wave;      // 12500*4 = 50000 exact
    const int half = lane >> 5;
    const int sl = lane & 31;

    const float4 hm = *(const float4*)(hM + (size_t)node * D + sl * 4);
    const int start = (node == 0) ? 0 : offsets[node - 1];  // post-scatter semantics
    const int end = offsets[node];

    float4 acc = {0.f, 0.f, 0.f, 0.f};
    for (int idx = start + half; idx < end; idx += 2) {
        const int d = sorted_dst[idx];                       // broadcast within half
        const float4 xv = *(const float4*)(X + (size_t)d * D + sl * 4); // 512B gather
        float t = hm.x * xv.x + hm.y * xv.y + hm.z * xv.z + hm.w * xv.w;
#pragma unroll
        for (int m = 1; m < 32; m <<= 1)                     // reduce within half
            t += __shfl_xor(t, m);
        const float e = t > 0.f ? t : NEG_SLOPE * t;
        acc.x = fmaf(e, xv.x, acc.x);
        acc.y = fmaf(e, xv.y, acc.y);
        acc.z = fmaf(e, xv.z, acc.z);
        acc.w = fmaf(e, xv.w, acc.w);
    }
    // combine the two halves
    acc.x += __shfl_xor(acc.x, 32);
    acc.y += __shfl_xor(acc.y, 32);
    acc.z += __shfl_xor(acc.z, 32);
    acc.w += __shfl_xor(acc.w, 32);
    if (half == 0)
        *(float4*)(aggX + (size_t)node * D + sl * 4) = acc;  // coalesced 512B store
}

extern "C" void kernel_launch(void* const* d_in, const int* in_sizes, int n_in,
                              void* d_out, int out_size, void* d_ws, size_t ws_size,
                              hipStream_t stream) {
    const float* X   = (const float*)d_in[0];
    const float* W   = (const float*)d_in[1];
    const float* W_r = (const float*)d_in[2];
    const float* W_l = (const float*)d_in[3];
    const int* src   = (const int*)d_in[4];
    const int* dst   = (const int*)d_in[5];
    float* agg = (float*)d_out;

    // workspace layout (~55 MB)
    float* hM        = (float*)d_ws;                      // 50000*128
    float* aggX      = hM + (size_t)N_NODES * D;          // 50000*128
    float* M         = aggX + (size_t)N_NODES * D;        // 128*128
    int*   counts    = (int*)(M + D * D);                 // 50000
    int*   offsets   = counts + N_NODES;                  // 50000
    int*   sorted_dst = offsets + N_NODES;                // 800000

    hipMemsetAsync(counts, 0, N_NODES * sizeof(int), stream);

    hist_kernel<<<N_EDGES / 256, 256, 0, stream>>>(src, counts);
    scan_kernel<<<1, 1024, 0, stream>>>(counts, offsets);
    scatter_kernel<<<N_EDGES / 256, 256, 0, stream>>>(src, dst, offsets, sorted_dst);

    wlwrt_kernel<<<128, 128, 0, stream>>>(W_l, W_r, M);
    dense_nn_kernel<<<N_NODES / 16, 256, 0, stream>>>(X, M, hM, N_NODES);

    spmm_kernel<<<N_NODES / 4, 256, 0, stream>>>(hM, X, offsets, sorted_dst, aggX);

    dense_nn_kernel<<<N_NODES / 16, 256, 0, stream>>>(aggX, W, agg, N_NODES);
}

// Round 3
// 307.841 us; speedup vs baseline: 3.6340x; 1.2728x over previous
//
#include <hip/hip_runtime.h>
#include <hip/hip_bf16.h>

#define N_NODES 50000
#define N_EDGES 800000
#define D 128
#define NEG_SLOPE 0.2f
#define SCAN_NBLK ((N_NODES + 255) / 256)   // 196

// ---------------- M = W_l @ W_r^T (128x128, tiny) ----------------
__global__ __launch_bounds__(128) void wlwrt_kernel(const float* __restrict__ W_l,
                                                    const float* __restrict__ W_r,
                                                    float* __restrict__ M) {
    const int a = blockIdx.x;      // row of M
    const int b = threadIdx.x;     // col of M
    float acc = 0.f;
#pragma unroll
    for (int c = 0; c < D; c += 4) {
        const float4 wl = *(const float4*)(W_l + a * D + c);   // wave-uniform
        const float4 wr = *(const float4*)(W_r + b * D + c);   // 64KB table, L1/L2-hot
        acc += wl.x * wr.x + wl.y * wr.y + wl.z * wr.z + wl.w * wr.w;
    }
    M[a * D + b] = acc;
}

// ---------------- C = A @ B   (A [nrows x 128] row-major, B [128 x 128]) ----
__global__ __launch_bounds__(256) void dense_nn_kernel(const float* __restrict__ A,
                                                       const float* __restrict__ B,
                                                       float* __restrict__ C,
                                                       int nrows) {
    __shared__ float As[16 * D];
    const int tid = threadIdx.x;
    const int c = tid & 127;
    const int half = tid >> 7;
    const int nb = blockIdx.x * 16;

    const float4* srcv = (const float4*)(A + (size_t)nb * D);
    float4* dstv = (float4*)As;
    dstv[tid] = srcv[tid];
    dstv[tid + 256] = srcv[tid + 256];
    __syncthreads();

    float acc[8] = {0, 0, 0, 0, 0, 0, 0, 0};
    for (int k = 0; k < D; k += 4) {
        const float m0 = B[(k + 0) * D + c];
        const float m1 = B[(k + 1) * D + c];
        const float m2 = B[(k + 2) * D + c];
        const float m3 = B[(k + 3) * D + c];
#pragma unroll
        for (int n = 0; n < 8; ++n) {
            const float4 xv = *(const float4*)&As[(half * 8 + n) * D + k]; // LDS broadcast
            acc[n] = fmaf(xv.x, m0, fmaf(xv.y, m1, fmaf(xv.z, m2, fmaf(xv.w, m3, acc[n]))));
        }
    }
#pragma unroll
    for (int n = 0; n < 8; ++n)
        C[(size_t)(nb + half * 8 + n) * D + c] = acc[n];
}

// ---------------- CSR build ----------------
__global__ __launch_bounds__(256) void hist_kernel(const int* __restrict__ src,
                                                   int* __restrict__ counts) {
    const int e = blockIdx.x * 256 + threadIdx.x;
    if (e < N_EDGES) atomicAdd(&counts[src[e]], 1);
}

// hierarchical scan, pass 1: per-block sums (196 blocks x 256)
__global__ __launch_bounds__(256) void blocksum_kernel(const int* __restrict__ counts,
                                                       int* __restrict__ blocksums) {
    __shared__ int s[256];
    const int t = threadIdx.x;
    const int i = blockIdx.x * 256 + t;
    s[t] = (i < N_NODES) ? counts[i] : 0;
    __syncthreads();
#pragma unroll
    for (int off = 128; off > 0; off >>= 1) {
        if (t < off) s[t] += s[t + off];
        __syncthreads();
    }
    if (t == 0) blocksums[blockIdx.x] = s[0];
}

// pass 2: single block scans the 196 block sums -> exclusive base per block
__global__ __launch_bounds__(256) void scanbase_kernel(const int* __restrict__ blocksums,
                                                       int* __restrict__ blockbase) {
    __shared__ int s[256];
    const int t = threadIdx.x;
    s[t] = (t < SCAN_NBLK) ? blocksums[t] : 0;
    __syncthreads();
#pragma unroll
    for (int off = 1; off < 256; off <<= 1) {
        const int v = (t >= off) ? s[t - off] : 0;
        __syncthreads();
        s[t] += v;
        __syncthreads();
    }
    if (t < SCAN_NBLK) blockbase[t] = (t == 0) ? 0 : s[t - 1];
}

// pass 3: in-block exclusive scan + block base -> offsets (exclusive starts)
__global__ __launch_bounds__(256) void scanfinal_kernel(const int* __restrict__ counts,
                                                        const int* __restrict__ blockbase,
                                                        int* __restrict__ offsets) {
    __shared__ int s[256];
    const int t = threadIdx.x;
    const int i = blockIdx.x * 256 + t;
    const int v0 = (i < N_NODES) ? counts[i] : 0;
    s[t] = v0;
    __syncthreads();
#pragma unroll
    for (int off = 1; off < 256; off <<= 1) {
        const int v = (t >= off) ? s[t - off] : 0;
        __syncthreads();
        s[t] += v;
        __syncthreads();
    }
    if (i < N_NODES) offsets[i] = blockbase[blockIdx.x] + s[t] - v0;
}

// scatter dst grouped by src; consumes offsets (post: offsets[i] = end of row i)
__global__ __launch_bounds__(256) void scatter_kernel(const int* __restrict__ src,
                                                      const int* __restrict__ dst,
                                                      int* __restrict__ offsets,
                                                      int* __restrict__ sorted_dst) {
    const int e = blockIdx.x * 256 + threadIdx.x;
    if (e < N_EDGES) {
        const int pos = atomicAdd(&offsets[src[e]], 1);
        sorted_dst[pos] = dst[e];
    }
}

// ---------------- fused SDDMM + SpMM, no atomics ----------------
__global__ __launch_bounds__(256) void spmm_kernel(const float* __restrict__ hM,
                                                   const float* __restrict__ X,
                                                   const int* __restrict__ offsets,
                                                   const int* __restrict__ sorted_dst,
                                                   float* __restrict__ aggX) {
    const int wave = threadIdx.x >> 6;
    const int lane = threadIdx.x & 63;
    const int node = blockIdx.x * 4 + wave;      // 12500*4 = 50000 exact
    const int half = lane >> 5;
    const int sl = lane & 31;

    const float4 hm = *(const float4*)(hM + (size_t)node * D + sl * 4);
    const int start = (node == 0) ? 0 : offsets[node - 1];  // post-scatter: end of prev row
    const int end = offsets[node];

    float4 acc = {0.f, 0.f, 0.f, 0.f};
    for (int idx = start + half; idx < end; idx += 2) {
        const int d = sorted_dst[idx];                       // broadcast within half
        const float4 xv = *(const float4*)(X + (size_t)d * D + sl * 4); // 512B gather
        float t = hm.x * xv.x + hm.y * xv.y + hm.z * xv.z + hm.w * xv.w;
#pragma unroll
        for (int m = 1; m < 32; m <<= 1)                     // reduce within half
            t += __shfl_xor(t, m);
        const float e = t > 0.f ? t : NEG_SLOPE * t;
        acc.x = fmaf(e, xv.x, acc.x);
        acc.y = fmaf(e, xv.y, acc.y);
        acc.z = fmaf(e, xv.z, acc.z);
        acc.w = fmaf(e, xv.w, acc.w);
    }
    acc.x += __shfl_xor(acc.x, 32);
    acc.y += __shfl_xor(acc.y, 32);
    acc.z += __shfl_xor(acc.z, 32);
    acc.w += __shfl_xor(acc.w, 32);
    if (half == 0)
        *(float4*)(aggX + (size_t)node * D + sl * 4) = acc;  // coalesced 512B store
}

extern "C" void kernel_launch(void* const* d_in, const int* in_sizes, int n_in,
                              void* d_out, int out_size, void* d_ws, size_t ws_size,
                              hipStream_t stream) {
    const float* X   = (const float*)d_in[0];
    const float* W   = (const float*)d_in[1];
    const float* W_r = (const float*)d_in[2];
    const float* W_l = (const float*)d_in[3];
    const int* src   = (const int*)d_in[4];
    const int* dst   = (const int*)d_in[5];
    float* agg = (float*)d_out;

    // workspace layout (~55 MB)
    float* hM         = (float*)d_ws;                     // 50000*128
    float* aggX       = hM + (size_t)N_NODES * D;         // 50000*128
    float* M          = aggX + (size_t)N_NODES * D;       // 128*128
    int*   counts     = (int*)(M + D * D);                // 50000
    int*   offsets    = counts + N_NODES;                 // 50000
    int*   sorted_dst = offsets + N_NODES;                // 800000
    int*   blocksums  = sorted_dst + N_EDGES;             // 196
    int*   blockbase  = blocksums + 256;                  // 196

    hipMemsetAsync(counts, 0, N_NODES * sizeof(int), stream);

    hist_kernel<<<N_EDGES / 256, 256, 0, stream>>>(src, counts);
    blocksum_kernel<<<SCAN_NBLK, 256, 0, stream>>>(counts, blocksums);
    scanbase_kernel<<<1, 256, 0, stream>>>(blocksums, blockbase);
    scanfinal_kernel<<<SCAN_NBLK, 256, 0, stream>>>(counts, blockbase, offsets);
    scatter_kernel<<<N_EDGES / 256, 256, 0, stream>>>(src, dst, offsets, sorted_dst);

    wlwrt_kernel<<<128, 128, 0, stream>>>(W_l, W_r, M);
    dense_nn_kernel<<<N_NODES / 16, 256, 0, stream>>>(X, M, hM, N_NODES);

    spmm_kernel<<<N_NODES / 4, 256, 0, stream>>>(hM, X, offsets, sorted_dst, aggX);

    dense_nn_kernel<<<N_NODES / 16, 256, 0, stream>>>(aggX, W, agg, N_NODES);
}

// Round 4
// 271.047 us; speedup vs baseline: 4.1273x; 1.1357x over previous
//
#include <hip/hip_runtime.h>
#include <hip/hip_bf16.h>

#define N_NODES 50000
#define N_EDGES 800000
#define D 128
#define NEG_SLOPE 0.2f
#define SCAN_NBLK ((N_NODES + 255) / 256)   // 196
#define APAD 136                             // LDS row pitch (ushort) -> 2-way-only conflicts

typedef __attribute__((ext_vector_type(8))) short bf16x8;
typedef __attribute__((ext_vector_type(4))) float f32x4;

__device__ inline unsigned short f2bf(float f) {
    union { float f; unsigned u; } v; v.f = f;
    const unsigned r = v.u + 0x7FFF + ((v.u >> 16) & 1);   // round-nearest-even
    return (unsigned short)(r >> 16);
}
__device__ inline float bf2f(unsigned short u) {
    union { unsigned u; float f; } v; v.u = (unsigned)u << 16;
    return v.f;
}
__device__ inline float4 bf4_to_f4(ushort4 u) {
    float4 f;
    f.x = bf2f(u.x); f.y = bf2f(u.y); f.z = bf2f(u.z); f.w = bf2f(u.w);
    return f;
}

// ---- X fp32 -> bf16 (1.6M float4s, grid exact) ----
__global__ __launch_bounds__(256) void convertX_kernel(const float4* __restrict__ X,
                                                       ushort4* __restrict__ Xb) {
    const int i = blockIdx.x * 256 + threadIdx.x;
    const float4 v = X[i];
    ushort4 o;
    o.x = f2bf(v.x); o.y = f2bf(v.y); o.z = f2bf(v.z); o.w = f2bf(v.w);
    Xb[i] = o;
}

// ---- MbT[n][k] = (W_l @ W_r^T)[k][n] in bf16; WbT[n][k] = W[k][n] in bf16 ----
__global__ __launch_bounds__(128) void prep_weights_kernel(const float* __restrict__ W_l,
                                                           const float* __restrict__ W_r,
                                                           const float* __restrict__ W,
                                                           ushort* __restrict__ MbT,
                                                           ushort* __restrict__ WbT) {
    const int a = blockIdx.x;      // k index
    const int b = threadIdx.x;     // n index
    float acc = 0.f;
#pragma unroll
    for (int c = 0; c < D; c += 4) {
        const float4 wl = *(const float4*)(W_l + a * D + c);   // wave-uniform
        const float4 wr = *(const float4*)(W_r + b * D + c);
        acc += wl.x * wr.x + wl.y * wr.y + wl.z * wr.z + wl.w * wr.w;
    }
    MbT[b * D + a] = f2bf(acc);
    WbT[b * D + a] = f2bf(W[a * D + b]);
}

// ---- C[nrows x 128] = A[nrows x 128] @ B[128 x 128], bf16 MFMA, fp32 acc ----
// BT is B transposed ([n][k]) so B-fragments are contiguous ds_read_b128.
template <bool OUT_F32>
__global__ __launch_bounds__(256) void mfma_gemm_kernel(const ushort* __restrict__ A,
                                                        const ushort* __restrict__ BT,
                                                        float* __restrict__ Cf,
                                                        ushort* __restrict__ Cb,
                                                        int nrows) {
    __shared__ __align__(16) unsigned short Bs[D * APAD];    // [n][k] padded
    __shared__ __align__(16) unsigned short As[64 * APAD];   // [row][k] padded
    const int tid = threadIdx.x;
    const int rb = blockIdx.x * 64;

    // stage BT: 128x128 ushort = 2048 float4, coalesced
#pragma unroll
    for (int i = 0; i < 8; ++i) {
        const int idx = tid + i * 256;
        const int row = idx >> 4;
        const int c8 = (idx & 15) << 3;
        const float4 v = ((const float4*)BT)[idx];
        *(float4*)&Bs[row * APAD + c8] = v;
    }
    // stage A: 64 rows x 128 ushort = 1024 float4 (row-guarded)
#pragma unroll
    for (int i = 0; i < 4; ++i) {
        const int idx = tid + i * 256;
        const int row = idx >> 4;
        const int c8 = (idx & 15) << 3;
        float4 v = {0.f, 0.f, 0.f, 0.f};
        if (rb + row < nrows)
            v = ((const float4*)(A + (size_t)(rb + row) * D))[idx & 15];
        *(float4*)&As[row * APAD + c8] = v;
    }
    __syncthreads();

    const int w = tid >> 6;
    const int lane = tid & 63;
    const int m = lane & 15;       // A row within wave-tile / C col
    const int kq = lane >> 4;      // k-quad

    f32x4 acc[8] = {};
    const unsigned short* Arow = &As[(w * 16 + m) * APAD + kq * 8];
#pragma unroll
    for (int kc = 0; kc < 4; ++kc) {
        const bf16x8 af = *(const bf16x8*)(Arow + kc * 32);
#pragma unroll
        for (int t = 0; t < 8; ++t) {
            const bf16x8 bf = *(const bf16x8*)&Bs[(t * 16 + m) * APAD + kc * 32 + kq * 8];
            acc[t] = __builtin_amdgcn_mfma_f32_16x16x32_bf16(af, bf, acc[t], 0, 0, 0);
        }
    }

    // C/D layout: col = lane&15, row = (lane>>4)*4 + reg  [m89-verified]
    const int orow0 = rb + w * 16 + kq * 4;
#pragma unroll
    for (int t = 0; t < 8; ++t) {
#pragma unroll
        for (int r = 0; r < 4; ++r) {
            const int row = orow0 + r;
            if (row < nrows) {
                const size_t o = (size_t)row * D + t * 16 + m;
                if (OUT_F32) Cf[o] = acc[t][r];
                else         Cb[o] = f2bf(acc[t][r]);
            }
        }
    }
}

// ---------------- CSR build ----------------
__global__ __launch_bounds__(256) void hist_kernel(const int* __restrict__ src,
                                                   int* __restrict__ counts) {
    const int e = blockIdx.x * 256 + threadIdx.x;
    if (e < N_EDGES) atomicAdd(&counts[src[e]], 1);
}

__global__ __launch_bounds__(256) void blocksum_kernel(const int* __restrict__ counts,
                                                       int* __restrict__ blocksums) {
    __shared__ int s[256];
    const int t = threadIdx.x;
    const int i = blockIdx.x * 256 + t;
    s[t] = (i < N_NODES) ? counts[i] : 0;
    __syncthreads();
#pragma unroll
    for (int off = 128; off > 0; off >>= 1) {
        if (t < off) s[t] += s[t + off];
        __syncthreads();
    }
    if (t == 0) blocksums[blockIdx.x] = s[0];
}

__global__ __launch_bounds__(256) void scanbase_kernel(const int* __restrict__ blocksums,
                                                       int* __restrict__ blockbase) {
    __shared__ int s[256];
    const int t = threadIdx.x;
    s[t] = (t < SCAN_NBLK) ? blocksums[t] : 0;
    __syncthreads();
#pragma unroll
    for (int off = 1; off < 256; off <<= 1) {
        const int v = (t >= off) ? s[t - off] : 0;
        __syncthreads();
        s[t] += v;
        __syncthreads();
    }
    if (t < SCAN_NBLK) blockbase[t] = (t == 0) ? 0 : s[t - 1];
}

__global__ __launch_bounds__(256) void scanfinal_kernel(const int* __restrict__ counts,
                                                        const int* __restrict__ blockbase,
                                                        int* __restrict__ offsets) {
    __shared__ int s[256];
    const int t = threadIdx.x;
    const int i = blockIdx.x * 256 + t;
    const int v0 = (i < N_NODES) ? counts[i] : 0;
    s[t] = v0;
    __syncthreads();
#pragma unroll
    for (int off = 1; off < 256; off <<= 1) {
        const int v = (t >= off) ? s[t - off] : 0;
        __syncthreads();
        s[t] += v;
        __syncthreads();
    }
    if (i < N_NODES) offsets[i] = blockbase[blockIdx.x] + s[t] - v0;
}

// post: offsets[i] = end of row i
__global__ __launch_bounds__(256) void scatter_kernel(const int* __restrict__ src,
                                                      const int* __restrict__ dst,
                                                      int* __restrict__ offsets,
                                                      int* __restrict__ sorted_dst) {
    const int e = blockIdx.x * 256 + threadIdx.x;
    if (e < N_EDGES) {
        const int pos = atomicAdd(&offsets[src[e]], 1);
        sorted_dst[pos] = dst[e];
    }
}

// ---- fused SDDMM + SpMM: bf16 gathers, fp32 math, bf16 output ----
__global__ __launch_bounds__(256) void spmm_kernel(const ushort* __restrict__ hMb,
                                                   const ushort* __restrict__ Xb,
                                                   const int* __restrict__ offsets,
                                                   const int* __restrict__ sorted_dst,
                                                   ushort* __restrict__ aggXb) {
    const int wave = threadIdx.x >> 6;
    const int lane = threadIdx.x & 63;
    const int node = blockIdx.x * 4 + wave;      // 12500*4 = 50000 exact
    const int half = lane >> 5;
    const int sl = lane & 31;

    const float4 hm = bf4_to_f4(*(const ushort4*)(hMb + (size_t)node * D + sl * 4));
    const int start = (node == 0) ? 0 : offsets[node - 1];
    const int end = offsets[node];

    float4 acc = {0.f, 0.f, 0.f, 0.f};
    for (int idx = start + half; idx < end; idx += 2) {
        const int d = sorted_dst[idx];
        const float4 xv = bf4_to_f4(*(const ushort4*)(Xb + (size_t)d * D + sl * 4)); // 256B gather
        float t = hm.x * xv.x + hm.y * xv.y + hm.z * xv.z + hm.w * xv.w;
#pragma unroll
        for (int mm = 1; mm < 32; mm <<= 1)
            t += __shfl_xor(t, mm);
        const float e = t > 0.f ? t : NEG_SLOPE * t;
        acc.x = fmaf(e, xv.x, acc.x);
        acc.y = fmaf(e, xv.y, acc.y);
        acc.z = fmaf(e, xv.z, acc.z);
        acc.w = fmaf(e, xv.w, acc.w);
    }
    acc.x += __shfl_xor(acc.x, 32);
    acc.y += __shfl_xor(acc.y, 32);
    acc.z += __shfl_xor(acc.z, 32);
    acc.w += __shfl_xor(acc.w, 32);
    if (half == 0) {
        ushort4 o;
        o.x = f2bf(acc.x); o.y = f2bf(acc.y); o.z = f2bf(acc.z); o.w = f2bf(acc.w);
        *(ushort4*)(aggXb + (size_t)node * D + sl * 4) = o;
    }
}

extern "C" void kernel_launch(void* const* d_in, const int* in_sizes, int n_in,
                              void* d_out, int out_size, void* d_ws, size_t ws_size,
                              hipStream_t stream) {
    const float* X   = (const float*)d_in[0];
    const float* W   = (const float*)d_in[1];
    const float* W_r = (const float*)d_in[2];
    const float* W_l = (const float*)d_in[3];
    const int* src   = (const int*)d_in[4];
    const int* dst   = (const int*)d_in[5];
    float* agg = (float*)d_out;

    // workspace (~42.2 MB)
    ushort* Xb        = (ushort*)d_ws;                    // 6.4M
    ushort* hMb       = Xb + (size_t)N_NODES * D;         // 6.4M
    ushort* aggXb     = hMb + (size_t)N_NODES * D;        // 6.4M
    ushort* MbT       = aggXb + (size_t)N_NODES * D;      // 16384
    ushort* WbT       = MbT + D * D;                      // 16384
    int*    counts    = (int*)(WbT + D * D);              // 50000
    int*    offsets   = counts + N_NODES;                 // 50000
    int*    sorted_dst = offsets + N_NODES;               // 800000
    int*    blocksums = sorted_dst + N_EDGES;             // 196
    int*    blockbase = blocksums + 256;                  // 196

    hipMemsetAsync(counts, 0, N_NODES * sizeof(int), stream);

    // CSR build
    hist_kernel<<<N_EDGES / 256, 256, 0, stream>>>(src, counts);
    blocksum_kernel<<<SCAN_NBLK, 256, 0, stream>>>(counts, blocksums);
    scanbase_kernel<<<1, 256, 0, stream>>>(blocksums, blockbase);
    scanfinal_kernel<<<SCAN_NBLK, 256, 0, stream>>>(counts, blockbase, offsets);
    scatter_kernel<<<N_EDGES / 256, 256, 0, stream>>>(src, dst, offsets, sorted_dst);

    // dense path (bf16)
    convertX_kernel<<<(N_NODES * D / 4) / 256, 256, 0, stream>>>((const float4*)X, (ushort4*)Xb);
    prep_weights_kernel<<<D, D, 0, stream>>>(W_l, W_r, W, MbT, WbT);

    const int ggrid = (N_NODES + 63) / 64;   // 782
    mfma_gemm_kernel<false><<<ggrid, 256, 0, stream>>>(Xb, MbT, nullptr, hMb, N_NODES);

    spmm_kernel<<<N_NODES / 4, 256, 0, stream>>>(hMb, Xb, offsets, sorted_dst, aggXb);

    mfma_gemm_kernel<true><<<ggrid, 256, 0, stream>>>(aggXb, WbT, agg, nullptr, N_NODES);
}

// Round 5
// 240.820 us; speedup vs baseline: 4.6453x; 1.1255x over previous
//
#include <hip/hip_runtime.h>
#include <hip/hip_bf16.h>

#define N_NODES 50000
#define N_EDGES 800000
#define D 128
#define NEG_SLOPE 0.2f
#define SCAN_NBLK ((N_NODES + 255) / 256)   // 196
#define SCATTER_NBLK (N_EDGES / 256)        // 3125
#define APAD 136                             // LDS row pitch (ushort) -> 2-way-only conflicts

typedef __attribute__((ext_vector_type(8))) short bf16x8;
typedef __attribute__((ext_vector_type(4))) float f32x4;

__device__ inline unsigned short f2bf(float f) {
    union { float f; unsigned u; } v; v.f = f;
    const unsigned r = v.u + 0x7FFF + ((v.u >> 16) & 1);   // round-nearest-even
    return (unsigned short)(r >> 16);
}
__device__ inline float bf2f(unsigned short u) {
    union { unsigned u; float f; } v; v.u = (unsigned)u << 16;
    return v.f;
}
__device__ inline unsigned fbits(float f) { union { float f; unsigned u; } v; v.f = f; return v.u; }
__device__ inline float ffrom(unsigned u) { union { unsigned u; float f; } v; v.u = u; return v.f; }

// unpack 8 bf16 (raw bits of float4) -> 8 fp32
__device__ inline void unpack8(const float4 raw, float* o) {
    const unsigned w0 = fbits(raw.x), w1 = fbits(raw.y), w2 = fbits(raw.z), w3 = fbits(raw.w);
    o[0] = ffrom(w0 << 16); o[1] = ffrom(w0 & 0xffff0000u);
    o[2] = ffrom(w1 << 16); o[3] = ffrom(w1 & 0xffff0000u);
    o[4] = ffrom(w2 << 16); o[5] = ffrom(w2 & 0xffff0000u);
    o[6] = ffrom(w3 << 16); o[7] = ffrom(w3 & 0xffff0000u);
}

// ---- fused: X fp32 -> bf16 (1.6M float4) + src histogram (first 800k threads) ----
__global__ __launch_bounds__(256) void convert_hist_kernel(const float4* __restrict__ X,
                                                           ushort4* __restrict__ Xb,
                                                           const int* __restrict__ src,
                                                           int* __restrict__ counts) {
    const int i = blockIdx.x * 256 + threadIdx.x;
    const float4 v = X[i];
    ushort4 o;
    o.x = f2bf(v.x); o.y = f2bf(v.y); o.z = f2bf(v.z); o.w = f2bf(v.w);
    Xb[i] = o;
    if (i < N_EDGES) atomicAdd(&counts[src[i]], 1);
}

// ---------------- hierarchical scan ----------------
__global__ __launch_bounds__(256) void blocksum_kernel(const int* __restrict__ counts,
                                                       int* __restrict__ blocksums) {
    __shared__ int s[256];
    const int t = threadIdx.x;
    const int i = blockIdx.x * 256 + t;
    s[t] = (i < N_NODES) ? counts[i] : 0;
    __syncthreads();
#pragma unroll
    for (int off = 128; off > 0; off >>= 1) {
        if (t < off) s[t] += s[t + off];
        __syncthreads();
    }
    if (t == 0) blocksums[blockIdx.x] = s[0];
}

__global__ __launch_bounds__(256) void scanbase_kernel(const int* __restrict__ blocksums,
                                                       int* __restrict__ blockbase) {
    __shared__ int s[256];
    const int t = threadIdx.x;
    s[t] = (t < SCAN_NBLK) ? blocksums[t] : 0;
    __syncthreads();
#pragma unroll
    for (int off = 1; off < 256; off <<= 1) {
        const int v = (t >= off) ? s[t - off] : 0;
        __syncthreads();
        s[t] += v;
        __syncthreads();
    }
    if (t < SCAN_NBLK) blockbase[t] = (t == 0) ? 0 : s[t - 1];
}

__global__ __launch_bounds__(256) void scanfinal_kernel(const int* __restrict__ counts,
                                                        const int* __restrict__ blockbase,
                                                        int* __restrict__ offsets) {
    __shared__ int s[256];
    const int t = threadIdx.x;
    const int i = blockIdx.x * 256 + t;
    const int v0 = (i < N_NODES) ? counts[i] : 0;
    s[t] = v0;
    __syncthreads();
#pragma unroll
    for (int off = 1; off < 256; off <<= 1) {
        const int v = (t >= off) ? s[t - off] : 0;
        __syncthreads();
        s[t] += v;
        __syncthreads();
    }
    if (i < N_NODES) offsets[i] = blockbase[blockIdx.x] + s[t] - v0;
}

// ---- fused: scatter (blocks 0..3124) + weight prep (blocks 3125..3188) ----
// post-scatter: offsets[i] = end of row i
__global__ __launch_bounds__(256) void scatter_prep_kernel(const int* __restrict__ src,
                                                           const int* __restrict__ dst,
                                                           int* __restrict__ offsets,
                                                           int* __restrict__ sorted_dst,
                                                           const float* __restrict__ W_l,
                                                           const float* __restrict__ W_r,
                                                           const float* __restrict__ W,
                                                           ushort* __restrict__ MbT,
                                                           ushort* __restrict__ WbT) {
    if (blockIdx.x < SCATTER_NBLK) {
        const int e = blockIdx.x * 256 + threadIdx.x;
        const int pos = atomicAdd(&offsets[src[e]], 1);
        sorted_dst[pos] = dst[e];
    } else {
        // MbT[n][k] = (W_l @ W_r^T)[k][n]; WbT[n][k] = W[k][n]
        const int a = (blockIdx.x - SCATTER_NBLK) * 2 + (threadIdx.x >> 7);  // k index
        const int b = threadIdx.x & 127;                                     // n index
        float acc = 0.f;
#pragma unroll
        for (int c = 0; c < D; c += 4) {
            const float4 wl = *(const float4*)(W_l + a * D + c);
            const float4 wr = *(const float4*)(W_r + b * D + c);
            acc += wl.x * wr.x + wl.y * wr.y + wl.z * wr.z + wl.w * wr.w;
        }
        MbT[b * D + a] = f2bf(acc);
        WbT[b * D + a] = f2bf(W[a * D + b]);
    }
}

// ---- C[nrows x 128] = A[nrows x 128] @ B[128 x 128], bf16 MFMA, fp32 acc ----
template <bool OUT_F32>
__global__ __launch_bounds__(256) void mfma_gemm_kernel(const ushort* __restrict__ A,
                                                        const ushort* __restrict__ BT,
                                                        float* __restrict__ Cf,
                                                        ushort* __restrict__ Cb,
                                                        int nrows) {
    __shared__ __align__(16) unsigned short Bs[D * APAD];    // [n][k] padded
    __shared__ __align__(16) unsigned short As[64 * APAD];   // [row][k] padded
    const int tid = threadIdx.x;
    const int rb = blockIdx.x * 64;

#pragma unroll
    for (int i = 0; i < 8; ++i) {
        const int idx = tid + i * 256;
        const int row = idx >> 4;
        const int c8 = (idx & 15) << 3;
        const float4 v = ((const float4*)BT)[idx];
        *(float4*)&Bs[row * APAD + c8] = v;
    }
#pragma unroll
    for (int i = 0; i < 4; ++i) {
        const int idx = tid + i * 256;
        const int row = idx >> 4;
        const int c8 = (idx & 15) << 3;
        float4 v = {0.f, 0.f, 0.f, 0.f};
        if (rb + row < nrows)
            v = ((const float4*)(A + (size_t)(rb + row) * D))[idx & 15];
        *(float4*)&As[row * APAD + c8] = v;
    }
    __syncthreads();

    const int w = tid >> 6;
    const int lane = tid & 63;
    const int m = lane & 15;
    const int kq = lane >> 4;

    f32x4 acc[8] = {};
    const unsigned short* Arow = &As[(w * 16 + m) * APAD + kq * 8];
#pragma unroll
    for (int kc = 0; kc < 4; ++kc) {
        const bf16x8 af = *(const bf16x8*)(Arow + kc * 32);
#pragma unroll
        for (int t = 0; t < 8; ++t) {
            const bf16x8 bf = *(const bf16x8*)&Bs[(t * 16 + m) * APAD + kc * 32 + kq * 8];
            acc[t] = __builtin_amdgcn_mfma_f32_16x16x32_bf16(af, bf, acc[t], 0, 0, 0);
        }
    }

    const int orow0 = rb + w * 16 + kq * 4;
#pragma unroll
    for (int t = 0; t < 8; ++t) {
#pragma unroll
        for (int r = 0; r < 4; ++r) {
            const int row = orow0 + r;
            if (row < nrows) {
                const size_t o = (size_t)row * D + t * 16 + m;
                if (OUT_F32) Cf[o] = acc[t][r];
                else         Cb[o] = f2bf(acc[t][r]);
            }
        }
    }
}

// ---- fused SDDMM + SpMM: quarter-wave per edge, 8 gathers in flight ----
__global__ __launch_bounds__(256) void spmm_kernel(const ushort* __restrict__ hMb,
                                                   const ushort* __restrict__ Xb,
                                                   const int* __restrict__ offsets,
                                                   const int* __restrict__ sorted_dst,
                                                   ushort* __restrict__ aggXb) {
    const int wave = threadIdx.x >> 6;
    const int lane = threadIdx.x & 63;
    const int node = blockIdx.x * 4 + wave;      // 12500*4 = 50000 exact
    const int q = lane >> 4;                     // quarter 0..3, one edge each
    const int ql = lane & 15;                    // lane in quarter; 16B each -> 256B row

    float hm[8];
    unpack8(*(const float4*)(hMb + (size_t)node * D + ql * 8), hm);

    const int start = (node == 0) ? 0 : offsets[node - 1];
    const int end = offsets[node];

    float acc[8] = {0.f, 0.f, 0.f, 0.f, 0.f, 0.f, 0.f, 0.f};

    int idx = start + q;
    while (idx + 4 < end) {                      // two edges per quarter: idx, idx+4
        const int d0 = sorted_dst[idx];
        const int d1 = sorted_dst[idx + 4];
        const float4 r0 = *(const float4*)(Xb + (size_t)d0 * D + ql * 8);
        const float4 r1 = *(const float4*)(Xb + (size_t)d1 * D + ql * 8);
        float x0[8], x1[8];
        unpack8(r0, x0);
        unpack8(r1, x1);
        float t0 = 0.f, t1 = 0.f;
#pragma unroll
        for (int j = 0; j < 8; ++j) { t0 = fmaf(hm[j], x0[j], t0); t1 = fmaf(hm[j], x1[j], t1); }
#pragma unroll
        for (int mm = 1; mm < 16; mm <<= 1) { t0 += __shfl_xor(t0, mm); t1 += __shfl_xor(t1, mm); }
        const float e0 = t0 > 0.f ? t0 : NEG_SLOPE * t0;
        const float e1 = t1 > 0.f ? t1 : NEG_SLOPE * t1;
#pragma unroll
        for (int j = 0; j < 8; ++j) { acc[j] = fmaf(e0, x0[j], acc[j]); acc[j] = fmaf(e1, x1[j], acc[j]); }
        idx += 8;
    }
    if (idx < end) {
        const int d0 = sorted_dst[idx];
        const float4 r0 = *(const float4*)(Xb + (size_t)d0 * D + ql * 8);
        float x0[8];
        unpack8(r0, x0);
        float t0 = 0.f;
#pragma unroll
        for (int j = 0; j < 8; ++j) t0 = fmaf(hm[j], x0[j], t0);
#pragma unroll
        for (int mm = 1; mm < 16; mm <<= 1) t0 += __shfl_xor(t0, mm);
        const float e0 = t0 > 0.f ? t0 : NEG_SLOPE * t0;
#pragma unroll
        for (int j = 0; j < 8; ++j) acc[j] = fmaf(e0, x0[j], acc[j]);
    }

    // combine quarters (xor 16, 32)
#pragma unroll
    for (int j = 0; j < 8; ++j) {
        acc[j] += __shfl_xor(acc[j], 16);
        acc[j] += __shfl_xor(acc[j], 32);
    }
    if (q == 0) {
        ushort4 o0, o1;
        o0.x = f2bf(acc[0]); o0.y = f2bf(acc[1]); o0.z = f2bf(acc[2]); o0.w = f2bf(acc[3]);
        o1.x = f2bf(acc[4]); o1.y = f2bf(acc[5]); o1.z = f2bf(acc[6]); o1.w = f2bf(acc[7]);
        ushort* outp = aggXb + (size_t)node * D + ql * 8;
        *(ushort4*)outp = o0;
        *(ushort4*)(outp + 4) = o1;
    }
}

extern "C" void kernel_launch(void* const* d_in, const int* in_sizes, int n_in,
                              void* d_out, int out_size, void* d_ws, size_t ws_size,
                              hipStream_t stream) {
    const float* X   = (const float*)d_in[0];
    const float* W   = (const float*)d_in[1];
    const float* W_r = (const float*)d_in[2];
    const float* W_l = (const float*)d_in[3];
    const int* src   = (const int*)d_in[4];
    const int* dst   = (const int*)d_in[5];
    float* agg = (float*)d_out;

    // workspace (~42.2 MB)
    ushort* Xb         = (ushort*)d_ws;                   // 6.4M
    ushort* hMb        = Xb + (size_t)N_NODES * D;        // 6.4M
    ushort* aggXb      = hMb + (size_t)N_NODES * D;       // 6.4M
    ushort* MbT        = aggXb + (size_t)N_NODES * D;     // 16384
    ushort* WbT        = MbT + D * D;                     // 16384
    int*    counts     = (int*)(WbT + D * D);             // 50000
    int*    offsets    = counts + N_NODES;                // 50000
    int*    sorted_dst = offsets + N_NODES;               // 800000
    int*    blocksums  = sorted_dst + N_EDGES;            // 196
    int*    blockbase  = blocksums + 256;                 // 196

    hipMemsetAsync(counts, 0, N_NODES * sizeof(int), stream);

    convert_hist_kernel<<<(N_NODES * D / 4) / 256, 256, 0, stream>>>(
        (const float4*)X, (ushort4*)Xb, src, counts);

    blocksum_kernel<<<SCAN_NBLK, 256, 0, stream>>>(counts, blocksums);
    scanbase_kernel<<<1, 256, 0, stream>>>(blocksums, blockbase);
    scanfinal_kernel<<<SCAN_NBLK, 256, 0, stream>>>(counts, blockbase, offsets);

    scatter_prep_kernel<<<SCATTER_NBLK + 64, 256, 0, stream>>>(
        src, dst, offsets, sorted_dst, W_l, W_r, W, MbT, WbT);

    const int ggrid = (N_NODES + 63) / 64;   // 782
    mfma_gemm_kernel<false><<<ggrid, 256, 0, stream>>>(Xb, MbT, nullptr, hMb, N_NODES);

    spmm_kernel<<<N_NODES / 4, 256, 0, stream>>>(hMb, Xb, offsets, sorted_dst, aggXb);

    mfma_gemm_kernel<true><<<ggrid, 256, 0, stream>>>(aggXb, WbT, agg, nullptr, N_NODES);
}

// Round 6
// 225.682 us; speedup vs baseline: 4.9569x; 1.0671x over previous
//
#include <hip/hip_runtime.h>
#include <hip/hip_bf16.h>

#define N_NODES 50000
#define N_EDGES 800000
#define D 128
#define NEG_SLOPE 0.2f
#define SCAN_NBLK ((N_NODES + 255) / 256)   // 196
#define APAD 136                             // LDS row pitch (ushort) -> 2-way-only conflicts

#define CB 49                                // coarse buckets: src >> 10
#define CHUNK 4096
#define BIN_NBLK ((N_EDGES + CHUNK - 1) / CHUNK)  // 196
#define PB_CAP 32768                         // pass-B LDS dst buffer (128KB)

typedef __attribute__((ext_vector_type(8))) short bf16x8;
typedef __attribute__((ext_vector_type(4))) float f32x4;

__device__ inline unsigned short f2bf(float f) {
    union { float f; unsigned u; } v; v.f = f;
    const unsigned r = v.u + 0x7FFF + ((v.u >> 16) & 1);   // round-nearest-even
    return (unsigned short)(r >> 16);
}
__device__ inline unsigned fbits(float f) { union { float f; unsigned u; } v; v.f = f; return v.u; }
__device__ inline float ffrom(unsigned u) { union { unsigned u; float f; } v; v.u = u; return v.f; }

// unpack 8 bf16 (raw bits of float4) -> 8 fp32
__device__ inline void unpack8(const float4 raw, float* o) {
    const unsigned w0 = fbits(raw.x), w1 = fbits(raw.y), w2 = fbits(raw.z), w3 = fbits(raw.w);
    o[0] = ffrom(w0 << 16); o[1] = ffrom(w0 & 0xffff0000u);
    o[2] = ffrom(w1 << 16); o[3] = ffrom(w1 & 0xffff0000u);
    o[4] = ffrom(w2 << 16); o[5] = ffrom(w2 & 0xffff0000u);
    o[6] = ffrom(w3 << 16); o[7] = ffrom(w3 & 0xffff0000u);
}

// ---- fused: X fp32 -> bf16 (1.6M float4) + src histogram (first 800k threads) ----
__global__ __launch_bounds__(256) void convert_hist_kernel(const float4* __restrict__ X,
                                                           ushort4* __restrict__ Xb,
                                                           const int* __restrict__ src,
                                                           int* __restrict__ counts) {
    const int i = blockIdx.x * 256 + threadIdx.x;
    const float4 v = X[i];
    ushort4 o;
    o.x = f2bf(v.x); o.y = f2bf(v.y); o.z = f2bf(v.z); o.w = f2bf(v.w);
    Xb[i] = o;
    if (i < N_EDGES) atomicAdd(&counts[src[i]], 1);
}

// ---------------- hierarchical scan ----------------
__global__ __launch_bounds__(256) void blocksum_kernel(const int* __restrict__ counts,
                                                       int* __restrict__ blocksums) {
    __shared__ int s[256];
    const int t = threadIdx.x;
    const int i = blockIdx.x * 256 + t;
    s[t] = (i < N_NODES) ? counts[i] : 0;
    __syncthreads();
#pragma unroll
    for (int off = 128; off > 0; off >>= 1) {
        if (t < off) s[t] += s[t + off];
        __syncthreads();
    }
    if (t == 0) blocksums[blockIdx.x] = s[0];
}

__global__ __launch_bounds__(256) void scanbase_kernel(const int* __restrict__ blocksums,
                                                       int* __restrict__ blockbase) {
    __shared__ int s[256];
    const int t = threadIdx.x;
    s[t] = (t < SCAN_NBLK) ? blocksums[t] : 0;
    __syncthreads();
#pragma unroll
    for (int off = 1; off < 256; off <<= 1) {
        const int v = (t >= off) ? s[t - off] : 0;
        __syncthreads();
        s[t] += v;
        __syncthreads();
    }
    if (t < SCAN_NBLK) blockbase[t] = (t == 0) ? 0 : s[t - 1];
}

// offsets[i] = exclusive start of node i (READ-ONLY afterwards);
// also seeds coarse bucket fill pointers: coarse_fill[b] = offsets[b<<10]
__global__ __launch_bounds__(256) void scanfinal_kernel(const int* __restrict__ counts,
                                                        const int* __restrict__ blockbase,
                                                        int* __restrict__ offsets,
                                                        int* __restrict__ coarse_fill) {
    __shared__ int s[256];
    const int t = threadIdx.x;
    const int i = blockIdx.x * 256 + t;
    const int v0 = (i < N_NODES) ? counts[i] : 0;
    s[t] = v0;
    __syncthreads();
#pragma unroll
    for (int off = 1; off < 256; off <<= 1) {
        const int v = (t >= off) ? s[t - off] : 0;
        __syncthreads();
        s[t] += v;
        __syncthreads();
    }
    if (i < N_NODES) {
        const int o = blockbase[blockIdx.x] + s[t] - v0;
        offsets[i] = o;
        if ((i & 1023) == 0) coarse_fill[i >> 10] = o;
    }
}

// ---- Pass A: LDS-staged coarse binning (blocks 0..BIN_NBLK-1) + weight prep ----
// binned[] ends up grouped by coarse bucket (bucket b occupies the global CSR
// range [offsets[b<<10], offsets[(b+1)<<10]) in arrival order).
__global__ __launch_bounds__(256) void bin_prep_kernel(const int* __restrict__ src,
                                                       const int* __restrict__ dst,
                                                       int* __restrict__ coarse_fill,
                                                       int2* __restrict__ binned,
                                                       const float* __restrict__ W_l,
                                                       const float* __restrict__ W_r,
                                                       const float* __restrict__ W,
                                                       ushort* __restrict__ MbT,
                                                       ushort* __restrict__ WbT) {
    if (blockIdx.x < BIN_NBLK) {
        __shared__ int hist[CB];
        __shared__ int bstart[CB];
        __shared__ int reserve[CB];
        __shared__ int fillL[CB];
        __shared__ int2 pairs[CHUNK];
        __shared__ int targ[CHUNK];
        const int t = threadIdx.x;
        const int e0 = blockIdx.x * CHUNK;

        if (t < CB) hist[t] = 0;
        __syncthreads();

        int s[16], d[16], b[16];
#pragma unroll
        for (int i = 0; i < 16; ++i) {
            const int e = e0 + i * 256 + t;
            if (e < N_EDGES) {
                s[i] = src[e]; d[i] = dst[e]; b[i] = s[i] >> 10;
                atomicAdd(&hist[b[i]], 1);
            } else b[i] = -1;
        }
        __syncthreads();
        if (t == 0) {                       // serial exclusive scan, 49 entries
            int run = 0;
            for (int j = 0; j < CB; ++j) { bstart[j] = run; run += hist[j]; }
        }
        __syncthreads();
        if (t < CB) {
            reserve[t] = atomicAdd(&coarse_fill[t], hist[t]);  // global range per bucket
            fillL[t] = bstart[t];
        }
        __syncthreads();
#pragma unroll
        for (int i = 0; i < 16; ++i) {
            if (b[i] >= 0) {
                const int p = atomicAdd(&fillL[b[i]], 1);      // chunk-local compacted pos
                pairs[p] = make_int2(s[i], d[i]);
                targ[p] = reserve[b[i]] + (p - bstart[b[i]]);  // consecutive within run
            }
        }
        __syncthreads();
        const int nval = min(CHUNK, N_EDGES - e0);
        for (int j = t; j < nval; j += 256)
            binned[targ[j]] = pairs[j];                        // coalesced run writes
    } else {
        // MbT[n][k] = (W_l @ W_r^T)[k][n]; WbT[n][k] = W[k][n]
        const int a = (blockIdx.x - BIN_NBLK) * 2 + (threadIdx.x >> 7);  // k index
        const int b2 = threadIdx.x & 127;                                // n index
        float acc = 0.f;
#pragma unroll
        for (int c = 0; c < D; c += 4) {
            const float4 wl = *(const float4*)(W_l + a * D + c);
            const float4 wr = *(const float4*)(W_r + b2 * D + c);
            acc += wl.x * wr.x + wl.y * wr.y + wl.z * wr.z + wl.w * wr.w;
        }
        MbT[b2 * D + a] = f2bf(acc);
        WbT[b2 * D + a] = f2bf(W[a * D + b2]);
    }
}

// ---- Pass B: fine scatter inside LDS, one block per coarse bucket ----
__global__ __launch_bounds__(256) void fine_scatter_kernel(const int2* __restrict__ binned,
                                                           const int* __restrict__ offsets,
                                                           int* __restrict__ sorted_dst) {
    __shared__ int dstbuf[PB_CAP];
    __shared__ int lfill[1024];
    const int b = blockIdx.x;                // 0..CB-1
    const int t = threadIdx.x;
    const int nodebase = b << 10;
    const int base = offsets[nodebase];
    const int end = (b == CB - 1) ? N_EDGES : offsets[nodebase + 1024];
    const int size = end - base;

    for (int i = t; i < 1024; i += 256) {
        const int n = nodebase + i;
        lfill[i] = (n < N_NODES) ? (offsets[n] - base) : 0;   // local starts
    }
    __syncthreads();

    if (size <= PB_CAP) {
        for (int e = base + t; e < end; e += 256) {
            const int2 sd = binned[e];
            const int p = atomicAdd(&lfill[sd.x - nodebase], 1);
            dstbuf[p] = sd.y;                                 // scatter stays in LDS
        }
        __syncthreads();
        for (int i = t; i < size; i += 256)
            sorted_dst[base + i] = dstbuf[i];                 // coalesced full-line writes
    } else {                                                  // safety fallback (never for this input)
        for (int e = base + t; e < end; e += 256) {
            const int2 sd = binned[e];
            const int p = atomicAdd(&lfill[sd.x - nodebase], 1);
            sorted_dst[base + p] = sd.y;
        }
    }
}

// ---- C[nrows x 128] = A[nrows x 128] @ B[128 x 128], bf16 MFMA, fp32 acc ----
template <bool OUT_F32>
__global__ __launch_bounds__(256) void mfma_gemm_kernel(const ushort* __restrict__ A,
                                                        const ushort* __restrict__ BT,
                                                        float* __restrict__ Cf,
                                                        ushort* __restrict__ Cb,
                                                        int nrows) {
    __shared__ __align__(16) unsigned short Bs[D * APAD];    // [n][k] padded
    __shared__ __align__(16) unsigned short As[64 * APAD];   // [row][k] padded
    const int tid = threadIdx.x;
    const int rb = blockIdx.x * 64;

#pragma unroll
    for (int i = 0; i < 8; ++i) {
        const int idx = tid + i * 256;
        const int row = idx >> 4;
        const int c8 = (idx & 15) << 3;
        const float4 v = ((const float4*)BT)[idx];
        *(float4*)&Bs[row * APAD + c8] = v;
    }
#pragma unroll
    for (int i = 0; i < 4; ++i) {
        const int idx = tid + i * 256;
        const int row = idx >> 4;
        const int c8 = (idx & 15) << 3;
        float4 v = {0.f, 0.f, 0.f, 0.f};
        if (rb + row < nrows)
            v = ((const float4*)(A + (size_t)(rb + row) * D))[idx & 15];
        *(float4*)&As[row * APAD + c8] = v;
    }
    __syncthreads();

    const int w = tid >> 6;
    const int lane = tid & 63;
    const int m = lane & 15;
    const int kq = lane >> 4;

    f32x4 acc[8] = {};
    const unsigned short* Arow = &As[(w * 16 + m) * APAD + kq * 8];
#pragma unroll
    for (int kc = 0; kc < 4; ++kc) {
        const bf16x8 af = *(const bf16x8*)(Arow + kc * 32);
#pragma unroll
        for (int t = 0; t < 8; ++t) {
            const bf16x8 bf = *(const bf16x8*)&Bs[(t * 16 + m) * APAD + kc * 32 + kq * 8];
            acc[t] = __builtin_amdgcn_mfma_f32_16x16x32_bf16(af, bf, acc[t], 0, 0, 0);
        }
    }

    const int orow0 = rb + w * 16 + kq * 4;
#pragma unroll
    for (int t = 0; t < 8; ++t) {
#pragma unroll
        for (int r = 0; r < 4; ++r) {
            const int row = orow0 + r;
            if (row < nrows) {
                const size_t o = (size_t)row * D + t * 16 + m;
                if (OUT_F32) Cf[o] = acc[t][r];
                else         Cb[o] = f2bf(acc[t][r]);
            }
        }
    }
}

// ---- fused SDDMM + SpMM: quarter-wave per edge, 8 gathers in flight ----
__global__ __launch_bounds__(256) void spmm_kernel(const ushort* __restrict__ hMb,
                                                   const ushort* __restrict__ Xb,
                                                   const int* __restrict__ offsets,
                                                   const int* __restrict__ sorted_dst,
                                                   ushort* __restrict__ aggXb) {
    const int wave = threadIdx.x >> 6;
    const int lane = threadIdx.x & 63;
    const int node = blockIdx.x * 4 + wave;      // 12500*4 = 50000 exact
    const int q = lane >> 4;                     // quarter 0..3, one edge each
    const int ql = lane & 15;                    // 16B per lane -> 256B row

    float hm[8];
    unpack8(*(const float4*)(hMb + (size_t)node * D + ql * 8), hm);

    const int start = offsets[node];             // offsets is exclusive starts now
    const int end = (node == N_NODES - 1) ? N_EDGES : offsets[node + 1];

    float acc[8] = {0.f, 0.f, 0.f, 0.f, 0.f, 0.f, 0.f, 0.f};

    int idx = start + q;
    while (idx + 4 < end) {                      // two edges per quarter
        const int d0 = sorted_dst[idx];
        const int d1 = sorted_dst[idx + 4];
        const float4 r0 = *(const float4*)(Xb + (size_t)d0 * D + ql * 8);
        const float4 r1 = *(const float4*)(Xb + (size_t)d1 * D + ql * 8);
        float x0[8], x1[8];
        unpack8(r0, x0);
        unpack8(r1, x1);
        float t0 = 0.f, t1 = 0.f;
#pragma unroll
        for (int j = 0; j < 8; ++j) { t0 = fmaf(hm[j], x0[j], t0); t1 = fmaf(hm[j], x1[j], t1); }
#pragma unroll
        for (int mm = 1; mm < 16; mm <<= 1) { t0 += __shfl_xor(t0, mm); t1 += __shfl_xor(t1, mm); }
        const float e0 = t0 > 0.f ? t0 : NEG_SLOPE * t0;
        const float e1 = t1 > 0.f ? t1 : NEG_SLOPE * t1;
#pragma unroll
        for (int j = 0; j < 8; ++j) { acc[j] = fmaf(e0, x0[j], acc[j]); acc[j] = fmaf(e1, x1[j], acc[j]); }
        idx += 8;
    }
    if (idx < end) {
        const int d0 = sorted_dst[idx];
        const float4 r0 = *(const float4*)(Xb + (size_t)d0 * D + ql * 8);
        float x0[8];
        unpack8(r0, x0);
        float t0 = 0.f;
#pragma unroll
        for (int j = 0; j < 8; ++j) t0 = fmaf(hm[j], x0[j], t0);
#pragma unroll
        for (int mm = 1; mm < 16; mm <<= 1) t0 += __shfl_xor(t0, mm);
        const float e0 = t0 > 0.f ? t0 : NEG_SLOPE * t0;
#pragma unroll
        for (int j = 0; j < 8; ++j) acc[j] = fmaf(e0, x0[j], acc[j]);
    }

#pragma unroll
    for (int j = 0; j < 8; ++j) {
        acc[j] += __shfl_xor(acc[j], 16);
        acc[j] += __shfl_xor(acc[j], 32);
    }
    if (q == 0) {
        ushort4 o0, o1;
        o0.x = f2bf(acc[0]); o0.y = f2bf(acc[1]); o0.z = f2bf(acc[2]); o0.w = f2bf(acc[3]);
        o1.x = f2bf(acc[4]); o1.y = f2bf(acc[5]); o1.z = f2bf(acc[6]); o1.w = f2bf(acc[7]);
        ushort* outp = aggXb + (size_t)node * D + ql * 8;
        *(ushort4*)outp = o0;
        *(ushort4*)(outp + 4) = o1;
    }
}

extern "C" void kernel_launch(void* const* d_in, const int* in_sizes, int n_in,
                              void* d_out, int out_size, void* d_ws, size_t ws_size,
                              hipStream_t stream) {
    const float* X   = (const float*)d_in[0];
    const float* W   = (const float*)d_in[1];
    const float* W_r = (const float*)d_in[2];
    const float* W_l = (const float*)d_in[3];
    const int* src   = (const int*)d_in[4];
    const int* dst   = (const int*)d_in[5];
    float* agg = (float*)d_out;

    // workspace (~48.5 MB)
    ushort* Xb         = (ushort*)d_ws;                   // 6.4M ushort
    ushort* hMb        = Xb + (size_t)N_NODES * D;        // 6.4M
    ushort* aggXb      = hMb + (size_t)N_NODES * D;       // 6.4M
    ushort* MbT        = aggXb + (size_t)N_NODES * D;     // 16384
    ushort* WbT        = MbT + D * D;                     // 16384
    int*    counts     = (int*)(WbT + D * D);             // 50000
    int*    offsets    = counts + N_NODES;                // 50000
    int*    sorted_dst = offsets + N_NODES;               // 800000
    int*    blocksums  = sorted_dst + N_EDGES;            // 256
    int*    blockbase  = blocksums + 256;                 // 256
    int*    coarse_fill = blockbase + 256;                // 64
    int2*   binned     = (int2*)(coarse_fill + 64);       // 800000 int2 (8B-aligned)

    hipMemsetAsync(counts, 0, N_NODES * sizeof(int), stream);

    convert_hist_kernel<<<(N_NODES * D / 4) / 256, 256, 0, stream>>>(
        (const float4*)X, (ushort4*)Xb, src, counts);

    blocksum_kernel<<<SCAN_NBLK, 256, 0, stream>>>(counts, blocksums);
    scanbase_kernel<<<1, 256, 0, stream>>>(blocksums, blockbase);
    scanfinal_kernel<<<SCAN_NBLK, 256, 0, stream>>>(counts, blockbase, offsets, coarse_fill);

    bin_prep_kernel<<<BIN_NBLK + 64, 256, 0, stream>>>(
        src, dst, coarse_fill, binned, W_l, W_r, W, MbT, WbT);
    fine_scatter_kernel<<<CB, 256, 0, stream>>>(binned, offsets, sorted_dst);

    const int ggrid = (N_NODES + 63) / 64;   // 782
    mfma_gemm_kernel<false><<<ggrid, 256, 0, stream>>>(Xb, MbT, nullptr, hMb, N_NODES);

    spmm_kernel<<<N_NODES / 4, 256, 0, stream>>>(hMb, Xb, offsets, sorted_dst, aggXb);

    mfma_gemm_kernel<true><<<ggrid, 256, 0, stream>>>(aggXb, WbT, agg, nullptr, N_NODES);
}

// Round 7
// 179.508 us; speedup vs baseline: 6.2320x; 1.2572x over previous
//
#include <hip/hip_runtime.h>
#include <hip/hip_bf16.h>

#define N_NODES 50000
#define N_EDGES 800000
#define D 128
#define NEG_SLOPE 0.2f
#define APAD 136                             // LDS row pitch (ushort) -> 2-way-only conflicts

#define FB 196                               // fine buckets: src >> 8 (256 nodes each)
#define BCAP 8192                            // per-bucket region capacity (avg fill 4096)
#define CHUNK 4096
#define BIN_NBLK ((N_EDGES + CHUNK - 1) / CHUNK)   // 196
#define CONV_NBLK (N_NODES * D / 4 / 256)    // 6250
#define GEMM_LDS ((D + 64) * APAD * 2)       // 52224 B: Bs[128][APAD] + As[64][APAD]

typedef __attribute__((ext_vector_type(8))) short bf16x8;
typedef __attribute__((ext_vector_type(4))) float f32x4;

__device__ inline unsigned short f2bf(float f) {
    union { float f; unsigned u; } v; v.f = f;
    const unsigned r = v.u + 0x7FFF + ((v.u >> 16) & 1);   // round-nearest-even
    return (unsigned short)(r >> 16);
}
__device__ inline unsigned fbits(float f) { union { float f; unsigned u; } v; v.f = f; return v.u; }
__device__ inline float ffrom(unsigned u) { union { unsigned u; float f; } v; v.u = u; return v.f; }

// unpack 8 bf16 (raw bits of float4) -> 8 fp32
__device__ inline void unpack8(const float4 raw, float* o) {
    const unsigned w0 = fbits(raw.x), w1 = fbits(raw.y), w2 = fbits(raw.z), w3 = fbits(raw.w);
    o[0] = ffrom(w0 << 16); o[1] = ffrom(w0 & 0xffff0000u);
    o[2] = ffrom(w1 << 16); o[3] = ffrom(w1 & 0xffff0000u);
    o[4] = ffrom(w2 << 16); o[5] = ffrom(w2 & 0xffff0000u);
    o[6] = ffrom(w3 << 16); o[7] = ffrom(w3 & 0xffff0000u);
}

// inclusive Hillis-Steele scan over 256 LDS entries; returns inclusive at t
__device__ inline int scan256_incl(int* arr, int t, int v) {
    arr[t] = v; __syncthreads();
#pragma unroll
    for (int off = 1; off < 256; off <<= 1) {
        const int u = (t >= off) ? arr[t - off] : 0;
        __syncthreads();
        arr[t] += u;
        __syncthreads();
    }
    return arr[t];
}

// ---- kernel 1: X fp32->bf16  +  weight prep (tail blocks)  +  zero bucket_fill ----
__global__ __launch_bounds__(256) void convert_prep_kernel(const float4* __restrict__ X,
                                                           ushort4* __restrict__ Xb,
                                                           const float* __restrict__ W_l,
                                                           const float* __restrict__ W_r,
                                                           const float* __restrict__ W,
                                                           ushort* __restrict__ MbT,
                                                           ushort* __restrict__ WbT,
                                                           int* __restrict__ bucket_fill) {
    if (blockIdx.x < CONV_NBLK) {
        const int i = blockIdx.x * 256 + threadIdx.x;
        const float4 v = X[i];
        ushort4 o;
        o.x = f2bf(v.x); o.y = f2bf(v.y); o.z = f2bf(v.z); o.w = f2bf(v.w);
        Xb[i] = o;
    } else {
        if (blockIdx.x == CONV_NBLK) bucket_fill[threadIdx.x] = 0;  // 256 entries
        // MbT[n][k] = (W_l @ W_r^T)[k][n]; WbT[n][k] = W[k][n]
        const int a = (blockIdx.x - CONV_NBLK) * 2 + (threadIdx.x >> 7);  // k index
        const int b2 = threadIdx.x & 127;                                 // n index
        float acc = 0.f;
#pragma unroll
        for (int c = 0; c < D; c += 4) {
            const float4 wl = *(const float4*)(W_l + a * D + c);
            const float4 wr = *(const float4*)(W_r + b2 * D + c);
            acc += wl.x * wr.x + wl.y * wr.y + wl.z * wr.z + wl.w * wr.w;
        }
        MbT[b2 * D + a] = f2bf(acc);
        WbT[b2 * D + a] = f2bf(W[a * D + b2]);
    }
}

// ---- kernel 2: chunk-staged binning into fixed-capacity bucket regions ----
__global__ __launch_bounds__(256) void bin_kernel(const int* __restrict__ src,
                                                  const int* __restrict__ dst,
                                                  int* __restrict__ bucket_fill,
                                                  int2* __restrict__ binned) {
    __shared__ int hist[256];
    __shared__ int bstart[256];
    __shared__ int reserveS[256];
    __shared__ int fillL[256];
    __shared__ int2 pairs[CHUNK];
    __shared__ int targ[CHUNK];
    const int t = threadIdx.x;
    const int e0 = blockIdx.x * CHUNK;

    hist[t] = 0;
    __syncthreads();

    int s[16], d[16], b[16];
#pragma unroll
    for (int i = 0; i < 16; ++i) {
        const int e = e0 + i * 256 + t;
        if (e < N_EDGES) {
            s[i] = src[e]; d[i] = dst[e]; b[i] = s[i] >> 8;
            atomicAdd(&hist[b[i]], 1);
        } else b[i] = -1;
    }
    __syncthreads();
    const int hv = hist[t];
    const int incl = scan256_incl(bstart, t, hv);   // bstart holds inclusive now
    const int mystart = incl - hv;
    reserveS[t] = hv ? atomicAdd(&bucket_fill[t], hv) : 0;
    __syncthreads();
    bstart[t] = mystart;                            // convert to exclusive
    fillL[t] = mystart;
    __syncthreads();
#pragma unroll
    for (int i = 0; i < 16; ++i) {
        if (b[i] >= 0) {
            const int p = atomicAdd(&fillL[b[i]], 1);           // chunk-local compacted pos
            pairs[p] = make_int2(s[i], d[i]);
            const int pos = reserveS[b[i]] + (p - bstart[b[i]]); // pos within bucket region
            targ[p] = (pos < BCAP) ? (b[i] * BCAP + pos) : -1;   // overflow guard (never hit)
        }
    }
    __syncthreads();
    const int nval = min(CHUNK, N_EDGES - e0);
    for (int j = t; j < nval; j += 256)
        if (targ[j] >= 0) binned[targ[j]] = pairs[j];            // coalesced run writes
}

// ---- shared GEMM body: C[nrows x 128] = A @ B (BT transposed), bf16 MFMA ----
template <bool OUT_F32>
__device__ __forceinline__ void gemm_body(char* smemraw, int blk,
                                          const ushort* __restrict__ A,
                                          const ushort* __restrict__ BT,
                                          float* __restrict__ Cf,
                                          ushort* __restrict__ Cb,
                                          int nrows) {
    unsigned short* Bs = (unsigned short*)smemraw;   // [128][APAD]
    unsigned short* As = Bs + D * APAD;              // [64][APAD]
    const int tid = threadIdx.x;
    const int rb = blk * 64;

#pragma unroll
    for (int i = 0; i < 8; ++i) {
        const int idx = tid + i * 256;
        const int row = idx >> 4;
        const int c8 = (idx & 15) << 3;
        const float4 v = ((const float4*)BT)[idx];
        *(float4*)&Bs[row * APAD + c8] = v;
    }
#pragma unroll
    for (int i = 0; i < 4; ++i) {
        const int idx = tid + i * 256;
        const int row = idx >> 4;
        const int c8 = (idx & 15) << 3;
        float4 v = {0.f, 0.f, 0.f, 0.f};
        if (rb + row < nrows)
            v = ((const float4*)(A + (size_t)(rb + row) * D))[idx & 15];
        *(float4*)&As[row * APAD + c8] = v;
    }
    __syncthreads();

    const int w = tid >> 6;
    const int lane = tid & 63;
    const int m = lane & 15;
    const int kq = lane >> 4;

    f32x4 acc[8] = {};
    const unsigned short* Arow = &As[(w * 16 + m) * APAD + kq * 8];
#pragma unroll
    for (int kc = 0; kc < 4; ++kc) {
        const bf16x8 af = *(const bf16x8*)(Arow + kc * 32);
#pragma unroll
        for (int t2 = 0; t2 < 8; ++t2) {
            const bf16x8 bf = *(const bf16x8*)&Bs[(t2 * 16 + m) * APAD + kc * 32 + kq * 8];
            acc[t2] = __builtin_amdgcn_mfma_f32_16x16x32_bf16(af, bf, acc[t2], 0, 0, 0);
        }
    }

    const int orow0 = rb + w * 16 + kq * 4;
#pragma unroll
    for (int t2 = 0; t2 < 8; ++t2) {
#pragma unroll
        for (int r = 0; r < 4; ++r) {
            const int row = orow0 + r;
            if (row < nrows) {
                const size_t o = (size_t)row * D + t2 * 16 + m;
                if (OUT_F32) Cf[o] = acc[t2][r];
                else         Cb[o] = f2bf(acc[t2][r]);
            }
        }
    }
}

// ---- kernel 3: fine scatter (blocks 0..FB-1) + gemm1 hM = Xb@M (blocks FB..) ----
__global__ __launch_bounds__(256) void fine_gemm1_kernel(const int2* __restrict__ binned,
                                                         const int* __restrict__ bucket_fill,
                                                         int* __restrict__ offsets,
                                                         int* __restrict__ sorted_dst,
                                                         const ushort* __restrict__ Xb,
                                                         const ushort* __restrict__ MbT,
                                                         ushort* __restrict__ hMb) {
    __shared__ __align__(16) char smem[GEMM_LDS];
    if (blockIdx.x >= FB) {
        gemm_body<false>(smem, blockIdx.x - FB, Xb, MbT, nullptr, hMb, N_NODES);
        return;
    }
    // fine path LDS overlay (36.8 KB of the 52 KB)
    int* cntS   = (int*)smem;        // 256: bucket counts -> inclusive scan
    int* nh     = cntS + 256;        // 256: node histogram
    int* ex     = nh + 256;          // 256: scan workspace
    int* fill   = ex + 256;          // 256: fill pointers
    int* dstbuf = fill + 256;        // 8192

    const int b = blockIdx.x;
    const int t = threadIdx.x;

    const int myc = (t < FB) ? bucket_fill[t] : 0;
    scan256_incl(cntS, t, myc);                       // cntS = inclusive bucket sums
    const int base = (b == 0) ? 0 : cntS[b - 1];
    int cnt = cntS[b] - base;
    if (cnt > BCAP) cnt = BCAP;                       // matches bin overflow guard

    nh[t] = 0;
    __syncthreads();
    const int2* bb = binned + (size_t)b * BCAP;
    for (int e = t; e < cnt; e += 256) atomicAdd(&nh[bb[e].x & 255], 1);
    __syncthreads();
    const int v = nh[t];
    const int incl2 = scan256_incl(ex, t, v);
    const int mystart = incl2 - v;
    const int node = b * 256 + t;
    if (node < N_NODES) offsets[node] = base + mystart;   // exclusive CSR starts
    fill[t] = mystart;
    __syncthreads();
    for (int e = t; e < cnt; e += 256) {
        const int2 sd = bb[e];
        const int p = atomicAdd(&fill[sd.x & 255], 1);
        dstbuf[p] = sd.y;                                  // scatter stays in LDS
    }
    __syncthreads();
    for (int j = t; j < cnt; j += 256)
        sorted_dst[base + j] = dstbuf[j];                  // coalesced full-line writes
}

// ---- kernel 5: agg = aggX @ W ----
__global__ __launch_bounds__(256) void gemm2_kernel(const ushort* __restrict__ A,
                                                    const ushort* __restrict__ BT,
                                                    float* __restrict__ Cf) {
    __shared__ __align__(16) char smem[GEMM_LDS];
    gemm_body<true>(smem, blockIdx.x, A, BT, Cf, nullptr, N_NODES);
}

// ---- kernel 4: fused SDDMM + SpMM, quarter-wave per edge, unroll 4 ----
__global__ __launch_bounds__(256) void spmm_kernel(const ushort* __restrict__ hMb,
                                                   const ushort* __restrict__ Xb,
                                                   const int* __restrict__ offsets,
                                                   const int* __restrict__ sorted_dst,
                                                   ushort* __restrict__ aggXb) {
    const int wave = threadIdx.x >> 6;
    const int lane = threadIdx.x & 63;
    const int node = blockIdx.x * 4 + wave;      // 12500*4 = 50000 exact
    const int q = lane >> 4;                     // quarter 0..3, one edge each
    const int ql = lane & 15;                    // 16B per lane -> 256B row

    float hm[8];
    unpack8(*(const float4*)(hMb + (size_t)node * D + ql * 8), hm);

    const int start = offsets[node];
    const int end = (node == N_NODES - 1) ? N_EDGES : offsets[node + 1];

    float acc[8] = {0.f, 0.f, 0.f, 0.f, 0.f, 0.f, 0.f, 0.f};

    int idx = start + q;
    while (idx + 12 < end) {                     // 4 edges per quarter in flight
        const int d0 = sorted_dst[idx];
        const int d1 = sorted_dst[idx + 4];
        const int d2 = sorted_dst[idx + 8];
        const int d3 = sorted_dst[idx + 12];
        const float4 r0 = *(const float4*)(Xb + (size_t)d0 * D + ql * 8);
        const float4 r1 = *(const float4*)(Xb + (size_t)d1 * D + ql * 8);
        const float4 r2 = *(const float4*)(Xb + (size_t)d2 * D + ql * 8);
        const float4 r3 = *(const float4*)(Xb + (size_t)d3 * D + ql * 8);
        float t0 = 0.f, t1 = 0.f, t2 = 0.f, t3 = 0.f;
        {
            float x[8];
            unpack8(r0, x);
#pragma unroll
            for (int j = 0; j < 8; ++j) t0 = fmaf(hm[j], x[j], t0);
            unpack8(r1, x);
#pragma unroll
            for (int j = 0; j < 8; ++j) t1 = fmaf(hm[j], x[j], t1);
            unpack8(r2, x);
#pragma unroll
            for (int j = 0; j < 8; ++j) t2 = fmaf(hm[j], x[j], t2);
            unpack8(r3, x);
#pragma unroll
            for (int j = 0; j < 8; ++j) t3 = fmaf(hm[j], x[j], t3);
        }
#pragma unroll
        for (int mm = 1; mm < 16; mm <<= 1) {
            t0 += __shfl_xor(t0, mm);
            t1 += __shfl_xor(t1, mm);
            t2 += __shfl_xor(t2, mm);
            t3 += __shfl_xor(t3, mm);
        }
        const float e0 = t0 > 0.f ? t0 : NEG_SLOPE * t0;
        const float e1 = t1 > 0.f ? t1 : NEG_SLOPE * t1;
        const float e2 = t2 > 0.f ? t2 : NEG_SLOPE * t2;
        const float e3 = t3 > 0.f ? t3 : NEG_SLOPE * t3;
        {
            float x[8];
            unpack8(r0, x);
#pragma unroll
            for (int j = 0; j < 8; ++j) acc[j] = fmaf(e0, x[j], acc[j]);
            unpack8(r1, x);
#pragma unroll
            for (int j = 0; j < 8; ++j) acc[j] = fmaf(e1, x[j], acc[j]);
            unpack8(r2, x);
#pragma unroll
            for (int j = 0; j < 8; ++j) acc[j] = fmaf(e2, x[j], acc[j]);
            unpack8(r3, x);
#pragma unroll
            for (int j = 0; j < 8; ++j) acc[j] = fmaf(e3, x[j], acc[j]);
        }
        idx += 16;
    }
    while (idx < end) {                          // per-quarter remainder
        const int d0 = sorted_dst[idx];
        const float4 r0 = *(const float4*)(Xb + (size_t)d0 * D + ql * 8);
        float x[8];
        unpack8(r0, x);
        float t0 = 0.f;
#pragma unroll
        for (int j = 0; j < 8; ++j) t0 = fmaf(hm[j], x[j], t0);
#pragma unroll
        for (int mm = 1; mm < 16; mm <<= 1) t0 += __shfl_xor(t0, mm);
        const float e0 = t0 > 0.f ? t0 : NEG_SLOPE * t0;
#pragma unroll
        for (int j = 0; j < 8; ++j) acc[j] = fmaf(e0, x[j], acc[j]);
        idx += 4;
    }

#pragma unroll
    for (int j = 0; j < 8; ++j) {
        acc[j] += __shfl_xor(acc[j], 16);
        acc[j] += __shfl_xor(acc[j], 32);
    }
    if (q == 0) {
        ushort4 o0, o1;
        o0.x = f2bf(acc[0]); o0.y = f2bf(acc[1]); o0.z = f2bf(acc[2]); o0.w = f2bf(acc[3]);
        o1.x = f2bf(acc[4]); o1.y = f2bf(acc[5]); o1.z = f2bf(acc[6]); o1.w = f2bf(acc[7]);
        ushort* outp = aggXb + (size_t)node * D + ql * 8;
        *(ushort4*)outp = o0;
        *(ushort4*)(outp + 4) = o1;
    }
}

extern "C" void kernel_launch(void* const* d_in, const int* in_sizes, int n_in,
                              void* d_out, int out_size, void* d_ws, size_t ws_size,
                              hipStream_t stream) {
    const float* X   = (const float*)d_in[0];
    const float* W   = (const float*)d_in[1];
    const float* W_r = (const float*)d_in[2];
    const float* W_l = (const float*)d_in[3];
    const int* src   = (const int*)d_in[4];
    const int* dst   = (const int*)d_in[5];
    float* agg = (float*)d_out;

    // workspace (~55 MB)
    ushort* Xb          = (ushort*)d_ws;                  // 6.4M ushort
    ushort* hMb         = Xb + (size_t)N_NODES * D;       // 6.4M
    ushort* aggXb       = hMb + (size_t)N_NODES * D;      // 6.4M
    ushort* MbT         = aggXb + (size_t)N_NODES * D;    // 16384
    ushort* WbT         = MbT + D * D;                    // 16384
    int*    offsets     = (int*)(WbT + D * D);            // 50000
    int*    sorted_dst  = offsets + N_NODES;              // 800000
    int*    bucket_fill = sorted_dst + N_EDGES;           // 256
    int2*   binned      = (int2*)(bucket_fill + 256);     // FB*BCAP int2 (8B-aligned)

    convert_prep_kernel<<<CONV_NBLK + 64, 256, 0, stream>>>(
        (const float4*)X, (ushort4*)Xb, W_l, W_r, W, MbT, WbT, bucket_fill);

    bin_kernel<<<BIN_NBLK, 256, 0, stream>>>(src, dst, bucket_fill, binned);

    fine_gemm1_kernel<<<FB + (N_NODES + 63) / 64, 256, 0, stream>>>(
        binned, bucket_fill, offsets, sorted_dst, Xb, MbT, hMb);

    spmm_kernel<<<N_NODES / 4, 256, 0, stream>>>(hMb, Xb, offsets, sorted_dst, aggXb);

    gemm2_kernel<<<(N_NODES + 63) / 64, 256, 0, stream>>>(aggXb, WbT, agg);
}